// Round 13
// baseline (221.340 us; speedup 1.0000x reference)
//
#include <hip/hip_runtime.h>

typedef __attribute__((ext_vector_type(8))) __bf16 bf16x8;
typedef __attribute__((ext_vector_type(8))) unsigned short u16x8;
typedef __attribute__((ext_vector_type(4))) float f32x4;

#define NEGV (-1e30f)

// ---------------------------------------------------------------------------
// Workspace layout (bytes):
//  Bh  : [1152][1024] bf16  @ 0          (2,359,296)
//  Bl  : [1152][1024] bf16  @ 2359296    (2,359,296)
//  Yh  : [8192][1024] bf16  @ 4718592    (16,777,216)  h_last * node_mask
//  LR  : [48][8192]  f32    @ 21495808   (1,572,864)   left/right, c = s*24+t*8+h
//  Vt  : [8][16][128][512] bf16 @ 23068672 (16,777,216) transposed h_last
//  adjB: [16][512][512] u8  @ 39845888   (4,194,304)
//  total 44,040,192 B
// ---------------------------------------------------------------------------

__device__ __forceinline__ unsigned short f2bf(float f) {
    unsigned int u = __float_as_uint(f);
    u += 0x7fffu + ((u >> 16) & 1u);
    return (unsigned short)(u >> 16);
}
__device__ __forceinline__ float b2f(unsigned short h) {
    return __uint_as_float(((unsigned int)h) << 16);
}

// ---------------------------------------------------------------------------
// Kernel 1: pack Bpt[n][k] (transposed, hi/lo bf16 split)  [unchanged]
// ---------------------------------------------------------------------------
__global__ __launch_bounds__(256) void pack_kernel(const float* __restrict__ W,
                                                   const float* __restrict__ a1,
                                                   const float* __restrict__ a2,
                                                   unsigned short* __restrict__ Bh,
                                                   unsigned short* __restrict__ Bl) {
    const int n = blockIdx.x;
    const int tid = threadIdx.x;
    if (n < 1024) {
        const int h = n >> 7, d = n & 127;
        const float* w = W + (size_t)(h * 3 + 2) * 1024 * 128 + d;
        for (int k = tid; k < 1024; k += 256) {
            float v = w[(size_t)k * 128];
            unsigned short hi = f2bf(v);
            Bh[(size_t)n * 1024 + k] = hi;
            Bl[(size_t)n * 1024 + k] = f2bf(v - b2f(hi));
        }
    } else if (n < 1072) {
        const int c = n - 1024;
        const int s = c / 24, rem = c % 24, t = rem >> 3, h = rem & 7;
        const float* a = (s ? a2 : a1) + (h * 3 + t) * 128;
        const float* wb = W + (size_t)(h * 3 + t) * 1024 * 128;
        for (int k = tid; k < 1024; k += 256) {
            const float4* wr4 = (const float4*)(wb + (size_t)k * 128);
            const float4* a4 = (const float4*)a;
            float acc = 0.f;
            #pragma unroll 8
            for (int dd = 0; dd < 32; ++dd) {
                float4 wv = wr4[dd], av = a4[dd];
                acc += wv.x * av.x + wv.y * av.y + wv.z * av.z + wv.w * av.w;
            }
            unsigned short hi = f2bf(acc);
            Bh[(size_t)n * 1024 + k] = hi;
            Bl[(size_t)n * 1024 + k] = f2bf(acc - b2f(hi));
        }
    } else {
        for (int k = tid; k < 1024; k += 256) {
            Bh[(size_t)n * 1024 + k] = 0;
            Bl[(size_t)n * 1024 + k] = 0;
        }
    }
}

// ---------------------------------------------------------------------------
// Kernel 2: bf16x3 MFMA GEMM, 128x128 tile, FRAGMENT-ORDER LDS (conflict-free,
//   r12-verified mapping) + DOUBLE-BUFFERED single-barrier pipeline:
//   per step: issue B gloads(t+1)->buf^1 and X f32 loads(t+1)->regs FIRST,
//   compute(t) from buf^0, then convert+ds_write A(t+1), ONE barrier.
//   Loads get the whole compute phase to land -> barrier drain is free.
//   LDS 64KB -> 2 blocks/CU. Wave w stages frags {2w,2w+1} of A and B.
// ---------------------------------------------------------------------------
__global__ __launch_bounds__(256, 2) void mgemm(const float* __restrict__ X,
                                                const unsigned short* __restrict__ Bh,
                                                const unsigned short* __restrict__ Bl,
                                                const float* __restrict__ nm,
                                                unsigned short* __restrict__ Yh,
                                                float* __restrict__ LR) {
    __shared__ __align__(16) unsigned short Ah[2][8 * 512];
    __shared__ __align__(16) unsigned short Al[2][8 * 512];
    __shared__ __align__(16) unsigned short Bhs[2][8 * 512];
    __shared__ __align__(16) unsigned short Bls[2][8 * 512];

    const int bid = blockIdx.x;                 // 0..575
    const int swz = (bid & 7) * 72 + (bid >> 3); // XCD-aware, bijective (576=8*72)
    const int nt = swz % 9, mt = swz / 9;
    const int n0 = nt * 128, m0 = mt * 128;

    const int tid = threadIdx.x;
    const int lane = tid & 63, w = tid >> 6;
    const int wr = w >> 1, wc = w & 1;
    const int fr = lane & 15, fq = lane >> 4;

    f32x4 acc[4][4];
    #pragma unroll
    for (int m = 0; m < 4; ++m)
        #pragma unroll
        for (int n = 0; n < 4; ++n) acc[m][n] = (f32x4){0.f, 0.f, 0.f, 0.f};

    // staging roles: wave w owns frags f0=2w, f1=2w+1 (A and B alike)
    const int f0 = 2 * w, f1 = 2 * w + 1;
    const unsigned short* gB0h = Bh + (size_t)(n0 + f0 * 16 + fr) * 1024 + fq * 8;
    const unsigned short* gB0l = Bl + (size_t)(n0 + f0 * 16 + fr) * 1024 + fq * 8;
    const unsigned short* gB1h = Bh + (size_t)(n0 + f1 * 16 + fr) * 1024 + fq * 8;
    const unsigned short* gB1l = Bl + (size_t)(n0 + f1 * 16 + fr) * 1024 + fq * 8;
    const float* gX0 = X + (size_t)(m0 + f0 * 16 + fr) * 1024 + fq * 8;
    const float* gX1 = X + (size_t)(m0 + f1 * 16 + fr) * 1024 + fq * 8;

#define GLD(src_, dst_) __builtin_amdgcn_global_load_lds( \
        (const __attribute__((address_space(1))) void*)(src_), \
        (__attribute__((address_space(3))) void*)(dst_), 16, 0, 0)

    // ---- prologue: stage step 0 into buf 0
    GLD(gB0h, &Bhs[0][f0 * 512 + lane * 8]);
    GLD(gB1h, &Bhs[0][f1 * 512 + lane * 8]);
    GLD(gB0l, &Bls[0][f0 * 512 + lane * 8]);
    GLD(gB1l, &Bls[0][f1 * 512 + lane * 8]);
    float4 x0a = *(const float4*)(gX0);
    float4 x0b = *(const float4*)(gX0 + 4);
    float4 x1a = *(const float4*)(gX1);
    float4 x1b = *(const float4*)(gX1 + 4);
    {
        float xf0[8] = {x0a.x, x0a.y, x0a.z, x0a.w, x0b.x, x0b.y, x0b.z, x0b.w};
        float xf1[8] = {x1a.x, x1a.y, x1a.z, x1a.w, x1b.x, x1b.y, x1b.z, x1b.w};
        u16x8 vh0, vl0, vh1, vl1;
        #pragma unroll
        for (int i = 0; i < 8; ++i) {
            unsigned short hi = f2bf(xf0[i]);
            vh0[i] = hi;
            vl0[i] = f2bf(xf0[i] - b2f(hi));
        }
        #pragma unroll
        for (int i = 0; i < 8; ++i) {
            unsigned short hi = f2bf(xf1[i]);
            vh1[i] = hi;
            vl1[i] = f2bf(xf1[i] - b2f(hi));
        }
        *(u16x8*)(&Ah[0][f0 * 512 + lane * 8]) = vh0;
        *(u16x8*)(&Al[0][f0 * 512 + lane * 8]) = vl0;
        *(u16x8*)(&Ah[0][f1 * 512 + lane * 8]) = vh1;
        *(u16x8*)(&Al[0][f1 * 512 + lane * 8]) = vl1;
    }
    __syncthreads();   // step-0 stage complete

    for (int k0 = 0; k0 < 1024; k0 += 32) {
        const int cur = (k0 >> 5) & 1;
        const int nxt = cur ^ 1;
        const bool more = (k0 < 992);

        // ---- issue next-step loads FIRST (latency hides under compute)
        if (more) {
            GLD(gB0h + k0 + 32, &Bhs[nxt][f0 * 512 + lane * 8]);
            GLD(gB1h + k0 + 32, &Bhs[nxt][f1 * 512 + lane * 8]);
            GLD(gB0l + k0 + 32, &Bls[nxt][f0 * 512 + lane * 8]);
            GLD(gB1l + k0 + 32, &Bls[nxt][f1 * 512 + lane * 8]);
            x0a = *(const float4*)(gX0 + k0 + 32);
            x0b = *(const float4*)(gX0 + k0 + 36);
            x1a = *(const float4*)(gX1 + k0 + 32);
            x1b = *(const float4*)(gX1 + k0 + 36);
        }

        // ---- compute current step: conflict-free frag reads + 48 MFMA
        bf16x8 amh[4], bnh[4];
        #pragma unroll
        for (int m = 0; m < 4; ++m)
            amh[m] = *(bf16x8*)(&Ah[cur][(wr * 4 + m) * 512 + lane * 8]);
        #pragma unroll
        for (int n = 0; n < 4; ++n)
            bnh[n] = *(bf16x8*)(&Bhs[cur][(wc * 4 + n) * 512 + lane * 8]);
        #pragma unroll
        for (int m = 0; m < 4; ++m)
            #pragma unroll
            for (int n = 0; n < 4; ++n)
                acc[m][n] = __builtin_amdgcn_mfma_f32_16x16x32_bf16(amh[m], bnh[n], acc[m][n], 0, 0, 0);

        bf16x8 bnl[4];
        #pragma unroll
        for (int n = 0; n < 4; ++n)
            bnl[n] = *(bf16x8*)(&Bls[cur][(wc * 4 + n) * 512 + lane * 8]);
        #pragma unroll
        for (int m = 0; m < 4; ++m)
            #pragma unroll
            for (int n = 0; n < 4; ++n)
                acc[m][n] = __builtin_amdgcn_mfma_f32_16x16x32_bf16(amh[m], bnl[n], acc[m][n], 0, 0, 0);

        bf16x8 aml[4];
        #pragma unroll
        for (int m = 0; m < 4; ++m)
            aml[m] = *(bf16x8*)(&Al[cur][(wr * 4 + m) * 512 + lane * 8]);
        #pragma unroll
        for (int m = 0; m < 4; ++m)
            #pragma unroll
            for (int n = 0; n < 4; ++n)
                acc[m][n] = __builtin_amdgcn_mfma_f32_16x16x32_bf16(aml[m], bnh[n], acc[m][n], 0, 0, 0);

        // ---- convert + write next A (X regs arrived during compute)
        if (more) {
            float xf0[8] = {x0a.x, x0a.y, x0a.z, x0a.w, x0b.x, x0b.y, x0b.z, x0b.w};
            float xf1[8] = {x1a.x, x1a.y, x1a.z, x1a.w, x1b.x, x1b.y, x1b.z, x1b.w};
            u16x8 vh0, vl0, vh1, vl1;
            #pragma unroll
            for (int i = 0; i < 8; ++i) {
                unsigned short hi = f2bf(xf0[i]);
                vh0[i] = hi;
                vl0[i] = f2bf(xf0[i] - b2f(hi));
            }
            #pragma unroll
            for (int i = 0; i < 8; ++i) {
                unsigned short hi = f2bf(xf1[i]);
                vh1[i] = hi;
                vl1[i] = f2bf(xf1[i] - b2f(hi));
            }
            *(u16x8*)(&Ah[nxt][f0 * 512 + lane * 8]) = vh0;
            *(u16x8*)(&Al[nxt][f0 * 512 + lane * 8]) = vl0;
            *(u16x8*)(&Ah[nxt][f1 * 512 + lane * 8]) = vh1;
            *(u16x8*)(&Al[nxt][f1 * 512 + lane * 8]) = vl1;
        }

        __syncthreads();   // single barrier per step (drain is cheap now)
    }
#undef GLD

    // ---- epilogue: C/D layout col=lane&15, row=(lane>>4)*4+reg
    #pragma unroll
    for (int m = 0; m < 4; ++m) {
        #pragma unroll
        for (int r = 0; r < 4; ++r) {
            const int R = m0 + wr * 64 + m * 16 + fq * 4 + r;
            const float mk = nm[R];
            #pragma unroll
            for (int n = 0; n < 4; ++n) {
                const int col = n0 + wc * 64 + n * 16 + fr;
                const float v = acc[m][n][r];
                if (col < 1024) {
                    Yh[(size_t)R * 1024 + col] = f2bf(v * mk);
                } else {
                    const int c = col - 1024;
                    if (c < 48) LR[(size_t)c * 8192 + R] = v;
                }
            }
        }
    }
}

// ---------------------------------------------------------------------------
// Kernel 3: transpose Yh -> Vt[h][b][d][j]  [unchanged]
// ---------------------------------------------------------------------------
__global__ __launch_bounds__(256) void vt_kernel(const unsigned short* __restrict__ Yh,
                                                 unsigned short* __restrict__ Vt) {
    __shared__ __align__(16) unsigned short tile[64 * 136];
    const int bid = blockIdx.x;
    const int jt = bid & 7, b = (bid >> 3) & 15, h = bid >> 7;
    const int j0 = jt * 64;
    const int tid = threadIdx.x;

    #pragma unroll
    for (int rep = 0; rep < 4; ++rep) {
        int idx = rep * 256 + tid;
        int j = idx >> 4, dc = (idx & 15) * 8;
        u16x8 v = *(const u16x8*)(Yh + (size_t)(b * 512 + j0 + j) * 1024 + h * 128 + dc);
        *(u16x8*)(tile + j * 136 + dc) = v;
    }
    __syncthreads();
    #pragma unroll
    for (int rep = 0; rep < 4; ++rep) {
        int idx = rep * 256 + tid;
        int d = idx >> 3, jc = (idx & 7) * 8;
        u16x8 o;
        #pragma unroll
        for (int q = 0; q < 8; ++q) o[q] = tile[(jc + q) * 136 + d];
        *(u16x8*)(Vt + ((size_t)(h * 16 + b) * 128 + d) * 512 + j0 + jc) = o;
    }
}

// ---------------------------------------------------------------------------
// Kernel 3b: adj int32 -> byte array adjB  [unchanged]
// ---------------------------------------------------------------------------
__global__ __launch_bounds__(256) void adjb_kernel(const int* __restrict__ adj,
                                                   unsigned char* __restrict__ adjB) {
    const int idx = blockIdx.x * 256 + threadIdx.x;
    const int4* s = (const int4*)(adj + (size_t)idx * 16);
    int4 v0 = s[0], v1 = s[1], v2 = s[2], v3 = s[3];
    union { unsigned char c[16]; int4 v; } o;
    o.c[0] = (unsigned char)v0.x; o.c[1] = (unsigned char)v0.y;
    o.c[2] = (unsigned char)v0.z; o.c[3] = (unsigned char)v0.w;
    o.c[4] = (unsigned char)v1.x; o.c[5] = (unsigned char)v1.y;
    o.c[6] = (unsigned char)v1.z; o.c[7] = (unsigned char)v1.w;
    o.c[8] = (unsigned char)v2.x; o.c[9] = (unsigned char)v2.y;
    o.c[10] = (unsigned char)v2.z; o.c[11] = (unsigned char)v2.w;
    o.c[12] = (unsigned char)v3.x; o.c[13] = (unsigned char)v3.y;
    o.c[14] = (unsigned char)v3.z; o.c[15] = (unsigned char)v3.w;
    *(int4*)(adjB + (size_t)idx * 16) = o.v;
}

// ---------------------------------------------------------------------------
// Kernel 4: fused attn  [unchanged — verified in round 10's 165us total]
// ---------------------------------------------------------------------------
__global__ __launch_bounds__(256, 4) void attn_kernel(const unsigned short* __restrict__ Vt,
                                                      const float* __restrict__ LR,
                                                      const unsigned char* __restrict__ adjB,
                                                      float* __restrict__ out) {
    __shared__ __align__(16) unsigned short Vb[2][16 * 512];
    __shared__ __align__(16) float rt[3 * 512];

    const int bid = blockIdx.x;
    const int itg = bid >> 7, hb = bid & 127, h = hb >> 4, b = hb & 15;
    const int tid = threadIdx.x, w = tid >> 6, lane = tid & 63;
    const int fr = lane & 15, fq = lane >> 4;
    const int i0 = (itg * 4 + w) * 16;
    const int fq8 = fq * 8;

    for (int idx = tid; idx < 1536; idx += 256) {
        int t = idx >> 9, j = idx & 511;
        rt[idx] = LR[(size_t)(24 + t * 8 + h) * 8192 + b * 512 + j];
    }
    const float lf0 = LR[(size_t)(h) * 8192 + b * 512 + i0 + fr];
    const float lf1 = LR[(size_t)(8 + h) * 8192 + b * 512 + i0 + fr];
    const float lf2 = LR[(size_t)(16 + h) * 8192 + b * 512 + i0 + fr];
    const unsigned char* arow = adjB + (size_t)(b * 512 + i0 + fr) * 512;
    const unsigned short* vt = Vt + (size_t)(h * 16 + b) * 128 * 512;

#define STAGE_V(bufp, os_) do {                                                   \
        _Pragma("unroll")                                                          \
        for (int q_ = 0; q_ < 4; ++q_) {                                           \
            const int nh_ = q_ * 4 + w;                                            \
            const unsigned short* src_ = vt + (size_t)((nh_ >> 1) * 16 + fr) * 512 \
                                          + (os_) * 64 + (nh_ & 1) * 32 + fq8;     \
            unsigned short* dst_ = (bufp) + nh_ * 512;                             \
            __builtin_amdgcn_global_load_lds(                                      \
                (const __attribute__((address_space(1))) void*)src_,               \
                (__attribute__((address_space(3))) void*)dst_, 16, 0, 0);          \
        }                                                                          \
    } while (0)

    STAGE_V(&Vb[0][0], 0);
    uint2 aA = *(const uint2*)(arow + fq8);
    uint2 aB = *(const uint2*)(arow + fq8 + 32);

    f32x4 acc[8];
    #pragma unroll
    for (int n = 0; n < 8; ++n) acc[n] = (f32x4){0.f, 0.f, 0.f, 0.f};
    float rsum = 0.f;

    __syncthreads();

    #pragma unroll 1
    for (int os = 0; os < 8; ++os) {
        unsigned short* vb = &Vb[os & 1][0];
        if (os < 7) STAGE_V(&Vb[(os & 1) ^ 1][0], os + 1);

        const int jA = os * 64 + fq8;
        const int jB = jA + 32;

        u16x8 vhA, vlA, vhB, vlB;
        {
            float4 r0a = *(const float4*)(rt + jA), r0b = *(const float4*)(rt + jA + 4);
            float4 r1a = *(const float4*)(rt + 512 + jA), r1b = *(const float4*)(rt + 512 + jA + 4);
            float4 r2a = *(const float4*)(rt + 1024 + jA), r2b = *(const float4*)(rt + 1024 + jA + 4);
            float e0[8] = {r0a.x, r0a.y, r0a.z, r0a.w, r0b.x, r0b.y, r0b.z, r0b.w};
            float e1[8] = {r1a.x, r1a.y, r1a.z, r1a.w, r1b.x, r1b.y, r1b.z, r1b.w};
            float e2[8] = {r2a.x, r2a.y, r2a.z, r2a.w, r2b.x, r2b.y, r2b.z, r2b.w};
            #pragma unroll
            for (int q = 0; q < 8; ++q) {
                unsigned av = ((q < 4 ? aA.x : aA.y) >> (8 * (q & 3))) & 255u;
                float sb = (av == 1u) ? (lf0 + e0[q])
                         : (av == 2u) ? (lf1 + e1[q]) : (lf2 + e2[q]);
                float sv = fmaxf(sb, 0.f) + 0.2f * fminf(sb, 0.f);
                float p = (av != 0u) ? __expf(sv) : 0.f;
                rsum += p;
                unsigned short hi = f2bf(p);
                vhA[q] = hi;
                vlA[q] = f2bf(p - b2f(hi));
            }
        }
        {
            float4 r0a = *(const float4*)(rt + jB), r0b = *(const float4*)(rt + jB + 4);
            float4 r1a = *(const float4*)(rt + 512 + jB), r1b = *(const float4*)(rt + 512 + jB + 4);
            float4 r2a = *(const float4*)(rt + 1024 + jB), r2b = *(const float4*)(rt + 1024 + jB + 4);
            float e0[8] = {r0a.x, r0a.y, r0a.z, r0a.w, r0b.x, r0b.y, r0b.z, r0b.w};
            float e1[8] = {r1a.x, r1a.y, r1a.z, r1a.w, r1b.x, r1b.y, r1b.z, r1b.w};
            float e2[8] = {r2a.x, r2a.y, r2a.z, r2a.w, r2b.x, r2b.y, r2b.z, r2b.w};
            #pragma unroll
            for (int q = 0; q < 8; ++q) {
                unsigned av = ((q < 4 ? aB.x : aB.y) >> (8 * (q & 3))) & 255u;
                float sb = (av == 1u) ? (lf0 + e0[q])
                         : (av == 2u) ? (lf1 + e1[q]) : (lf2 + e2[q]);
                float sv = fmaxf(sb, 0.f) + 0.2f * fminf(sb, 0.f);
                float p = (av != 0u) ? __expf(sv) : 0.f;
                rsum += p;
                unsigned short hi = f2bf(p);
                vhB[q] = hi;
                vlB[q] = f2bf(p - b2f(hi));
            }
        }
        if (os < 7) {
            aA = *(const uint2*)(arow + (os + 1) * 64 + fq8);
            aB = *(const uint2*)(arow + (os + 1) * 64 + fq8 + 32);
        }

        bf16x8 ahA = *(bf16x8*)&vhA, alA = *(bf16x8*)&vlA;
        bf16x8 ahB = *(bf16x8*)&vhB, alB = *(bf16x8*)&vlB;

        #pragma unroll
        for (int n = 0; n < 8; ++n) {
            bf16x8 vA = *(bf16x8*)(vb + (n * 2 + 0) * 512 + lane * 8);
            bf16x8 vB = *(bf16x8*)(vb + (n * 2 + 1) * 512 + lane * 8);
            acc[n] = __builtin_amdgcn_mfma_f32_16x16x32_bf16(ahA, vA, acc[n], 0, 0, 0);
            acc[n] = __builtin_amdgcn_mfma_f32_16x16x32_bf16(alA, vA, acc[n], 0, 0, 0);
            acc[n] = __builtin_amdgcn_mfma_f32_16x16x32_bf16(ahB, vB, acc[n], 0, 0, 0);
            acc[n] = __builtin_amdgcn_mfma_f32_16x16x32_bf16(alB, vB, acc[n], 0, 0, 0);
        }
        __syncthreads();
    }
#undef STAGE_V

    rsum += __shfl_xor(rsum, 16);
    rsum += __shfl_xor(rsum, 32);

    #pragma unroll
    for (int rr = 0; rr < 4; ++rr) {
        const int row = fq * 4 + rr;
        const float inv = 1.0f / __shfl(rsum, row);
        #pragma unroll
        for (int n = 0; n < 8; ++n) {
            out[(size_t)(b * 512 + i0 + row) * 1024 + h * 128 + n * 16 + fr] =
                fmaxf(acc[n][rr] * inv, 0.f);
        }
    }
}

// ---------------------------------------------------------------------------
extern "C" void kernel_launch(void* const* d_in, const int* in_sizes, int n_in,
                              void* d_out, int out_size, void* d_ws, size_t ws_size,
                              hipStream_t stream) {
    const float* x   = (const float*)d_in[0];
    const int*   adj = (const int*)d_in[1];
    const float* nm  = (const float*)d_in[2];
    const float* W   = (const float*)d_in[3];
    const float* a1  = (const float*)d_in[4];
    const float* a2  = (const float*)d_in[5];
    float* out = (float*)d_out;
    char* wsb = (char*)d_ws;

    unsigned short* Bh   = (unsigned short*)(wsb);
    unsigned short* Bl   = (unsigned short*)(wsb + 2359296);
    unsigned short* Yh   = (unsigned short*)(wsb + 4718592);
    float*          LR   = (float*)(wsb + 21495808);
    unsigned short* Vt   = (unsigned short*)(wsb + 23068672);
    unsigned char*  adjB = (unsigned char*)(wsb + 39845888);

    hipLaunchKernelGGL(adjb_kernel, dim3(1024), dim3(256), 0, stream, adj, adjB);
    hipLaunchKernelGGL(pack_kernel, dim3(1152), dim3(256), 0, stream, W, a1, a2, Bh, Bl);
    hipLaunchKernelGGL(mgemm, dim3(576), dim3(256), 0, stream, x, Bh, Bl, nm, Yh, LR);
    hipLaunchKernelGGL(vt_kernel, dim3(1024), dim3(256), 0, stream, Yh, Vt);
    hipLaunchKernelGGL(attn_kernel, dim3(1024), dim3(256), 0, stream, Vt, LR, adjB, out);
}

// Round 14
// 146.343 us; speedup vs baseline: 1.5125x; 1.5125x over previous
//
#include <hip/hip_runtime.h>

typedef __attribute__((ext_vector_type(8))) __bf16 bf16x8;
typedef __attribute__((ext_vector_type(8))) unsigned short u16x8;
typedef __attribute__((ext_vector_type(4))) unsigned short u16x4;
typedef __attribute__((ext_vector_type(4))) float f32x4;

#define NEGV (-1e30f)

// ---------------------------------------------------------------------------
// Workspace layout (bytes):
//  Bh  : [1152][1024] bf16  @ 0          (2,359,296)
//  Bl  : [1152][1024] bf16  @ 2359296    (2,359,296)
//  (Yh region @4718592 now unused)
//  LR  : [48][8192]  f32    @ 21495808   (1,572,864)
//  Vt  : [8][16][128][512] bf16 @ 23068672 (16,777,216)  written by mgemm
//  adjB: [16][512][512] u8  @ 39845888   (4,194,304)
//  total 44,040,192 B
// ---------------------------------------------------------------------------

__device__ __forceinline__ unsigned short f2bf(float f) {
    unsigned int u = __float_as_uint(f);
    u += 0x7fffu + ((u >> 16) & 1u);
    return (unsigned short)(u >> 16);
}
__device__ __forceinline__ float b2f(unsigned short h) {
    return __uint_as_float(((unsigned int)h) << 16);
}

// ---------------------------------------------------------------------------
// Kernel 1a: pack W_last columns via LDS transpose (coalesced W reads).
//   Bh/Bl[n=h*128+d][k] = split(W[h,2,k,d]).  grid 128 = 8h x 16 ktiles.
// ---------------------------------------------------------------------------
__global__ __launch_bounds__(256) void pack_tr(const float* __restrict__ W,
                                               unsigned short* __restrict__ Bh,
                                               unsigned short* __restrict__ Bl) {
    __shared__ float tile[64 * 133];
    const int bid = blockIdx.x;
    const int kt = bid & 15, h = bid >> 4;
    const int k0 = kt * 64;
    const int tid = threadIdx.x;
    const float* wsrc = W + ((size_t)((h * 3 + 2) * 1024) + k0) * 128;

    #pragma unroll
    for (int rep = 0; rep < 8; ++rep) {
        int idx = rep * 256 + tid;           // 2048 float4 chunks
        int k = idx >> 5, dc = (idx & 31) * 4;
        float4 v = *(const float4*)(wsrc + (size_t)k * 128 + dc);
        tile[k * 133 + dc + 0] = v.x;
        tile[k * 133 + dc + 1] = v.y;
        tile[k * 133 + dc + 2] = v.z;
        tile[k * 133 + dc + 3] = v.w;
    }
    __syncthreads();
    #pragma unroll
    for (int rep = 0; rep < 4; ++rep) {
        int idx = rep * 256 + tid;           // 1024 tasks: 128 d x 8 k-chunks
        int d = idx >> 3, kc = (idx & 7) * 8;
        u16x8 vh, vl;
        #pragma unroll
        for (int q = 0; q < 8; ++q) {
            float f = tile[(kc + q) * 133 + d];
            unsigned short hi = f2bf(f);
            vh[q] = hi;
            vl[q] = f2bf(f - b2f(hi));
        }
        size_t o = (size_t)(h * 128 + d) * 1024 + k0 + kc;
        *(u16x8*)(Bh + o) = vh;
        *(u16x8*)(Bl + o) = vl;
    }
}

// ---------------------------------------------------------------------------
// Kernel 1b: pack W.a columns (c = s*24 + t*8 + h) via LDS-staged matvec.
//   grid 384 = (t,h) 24 x 16 ktiles. W read once, coalesced.
// ---------------------------------------------------------------------------
__global__ __launch_bounds__(256) void pack_wa(const float* __restrict__ W,
                                               const float* __restrict__ a1,
                                               const float* __restrict__ a2,
                                               unsigned short* __restrict__ Bh,
                                               unsigned short* __restrict__ Bl) {
    __shared__ float tile[64 * 133];
    const int bid = blockIdx.x;
    const int kt = bid & 15, ht = bid >> 4;   // ht 0..23
    const int h = ht & 7, t = ht >> 3;
    const int k0 = kt * 64;
    const int tid = threadIdx.x;
    const float* wsrc = W + ((size_t)((h * 3 + t) * 1024) + k0) * 128;

    #pragma unroll
    for (int rep = 0; rep < 8; ++rep) {
        int idx = rep * 256 + tid;
        int k = idx >> 5, dc = (idx & 31) * 4;
        float4 v = *(const float4*)(wsrc + (size_t)k * 128 + dc);
        tile[k * 133 + dc + 0] = v.x;
        tile[k * 133 + dc + 1] = v.y;
        tile[k * 133 + dc + 2] = v.z;
        tile[k * 133 + dc + 3] = v.w;
    }
    __syncthreads();
    if (tid < 128) {
        const int k = tid & 63, s = tid >> 6;
        const float* ar = (s ? a2 : a1) + (h * 3 + t) * 128;
        float acc = 0.f;
        #pragma unroll 4
        for (int d = 0; d < 128; ++d) acc += tile[k * 133 + d] * ar[d];
        unsigned short hi = f2bf(acc);
        size_t o = (size_t)(1024 + s * 24 + t * 8 + h) * 1024 + k0 + k;
        Bh[o] = hi;
        Bl[o] = f2bf(acc - b2f(hi));
    }
}

// ---------------------------------------------------------------------------
// Kernel 1c: zero pad columns 1072..1151
// ---------------------------------------------------------------------------
__global__ __launch_bounds__(256) void pack_zero(unsigned short* __restrict__ Bh,
                                                 unsigned short* __restrict__ Bl) {
    const int n = 1072 + blockIdx.x;
    const int tid = threadIdx.x;
    *(unsigned long long*)(Bh + (size_t)n * 1024 + tid * 4) = 0ull;
    *(unsigned long long*)(Bl + (size_t)n * 1024 + tid * 4) = 0ull;
}

// ---------------------------------------------------------------------------
// Kernel 2: bf16x3 MFMA GEMM — r10-exact core (proven 92us), epilogue writes
//   Vt directly (h/b constant per block; per-(m,n) u16x4 packed store).
// ---------------------------------------------------------------------------
__global__ __launch_bounds__(256, 3) void mgemm(const float* __restrict__ X,
                                                const unsigned short* __restrict__ Bh,
                                                const unsigned short* __restrict__ Bl,
                                                const float* __restrict__ nm,
                                                unsigned short* __restrict__ Vt,
                                                float* __restrict__ LR) {
    __shared__ unsigned short Ah[128 * 32];
    __shared__ unsigned short Al[128 * 32];
    __shared__ unsigned short Bhs[128 * 32];
    __shared__ unsigned short Bls[128 * 32];

    const int bid = blockIdx.x;                 // 0..575
    const int swz = (bid & 7) * 72 + (bid >> 3); // XCD-aware, bijective
    const int nt = swz % 9, mt = swz / 9;
    const int n0 = nt * 128, m0 = mt * 128;

    const int tid = threadIdx.x;
    const int lane = tid & 63, w = tid >> 6;
    const int wr = w >> 1, wc = w & 1;
    const int fr = lane & 15, fq = lane >> 4;

    f32x4 acc[4][4];
    #pragma unroll
    for (int m = 0; m < 4; ++m)
        #pragma unroll
        for (int n = 0; n < 4; ++n) acc[m][n] = (f32x4){0.f, 0.f, 0.f, 0.f};

    const int arow = tid >> 1, ahalf = tid & 1;
    const float* xs = X + (size_t)(m0 + arow) * 1024 + ahalf * 16;
    unsigned short* adh = Ah + arow * 32 + ahalf * 16;
    unsigned short* adl = Al + arow * 32 + ahalf * 16;

    for (int k0 = 0; k0 < 1024; k0 += 32) {
        __syncthreads();

        #pragma unroll
        for (int q = 0; q < 2; ++q) {
            const int s = q * 256 + tid;
            const int brow = s >> 2, bkb = s & 3;
            const unsigned short* gh = Bh + (size_t)(n0 + brow) * 1024 + k0 + bkb * 8;
            const unsigned short* gl = Bl + (size_t)(n0 + brow) * 1024 + k0 + bkb * 8;
            unsigned short* dh = Bhs + (q * 256 + w * 64) * 8;
            unsigned short* dl = Bls + (q * 256 + w * 64) * 8;
            __builtin_amdgcn_global_load_lds(
                (const __attribute__((address_space(1))) void*)gh,
                (__attribute__((address_space(3))) void*)dh, 16, 0, 0);
            __builtin_amdgcn_global_load_lds(
                (const __attribute__((address_space(1))) void*)gl,
                (__attribute__((address_space(3))) void*)dl, 16, 0, 0);
        }

        float xf[16];
        #pragma unroll
        for (int i = 0; i < 4; ++i) {
            float4 v = *(const float4*)(xs + k0 + i * 4);
            xf[i * 4 + 0] = v.x; xf[i * 4 + 1] = v.y;
            xf[i * 4 + 2] = v.z; xf[i * 4 + 3] = v.w;
        }
        u16x8 vh0, vh1, vl0, vl1;
        #pragma unroll
        for (int i = 0; i < 8; ++i) {
            unsigned short hi = f2bf(xf[i]);
            vh0[i] = hi;
            vl0[i] = f2bf(xf[i] - b2f(hi));
        }
        #pragma unroll
        for (int i = 0; i < 8; ++i) {
            unsigned short hi = f2bf(xf[8 + i]);
            vh1[i] = hi;
            vl1[i] = f2bf(xf[8 + i] - b2f(hi));
        }
        *(u16x8*)(adh) = vh0;
        *(u16x8*)(adh + 8) = vh1;
        *(u16x8*)(adl) = vl0;
        *(u16x8*)(adl + 8) = vl1;

        __syncthreads();

        bf16x8 amh[4], bnh[4];
        #pragma unroll
        for (int m = 0; m < 4; ++m)
            amh[m] = *(bf16x8*)(Ah + (wr * 64 + m * 16 + fr) * 32 + fq * 8);
        #pragma unroll
        for (int n = 0; n < 4; ++n)
            bnh[n] = *(bf16x8*)(Bhs + (wc * 64 + n * 16 + fr) * 32 + fq * 8);
        #pragma unroll
        for (int m = 0; m < 4; ++m)
            #pragma unroll
            for (int n = 0; n < 4; ++n)
                acc[m][n] = __builtin_amdgcn_mfma_f32_16x16x32_bf16(amh[m], bnh[n], acc[m][n], 0, 0, 0);

        bf16x8 bnl[4];
        #pragma unroll
        for (int n = 0; n < 4; ++n)
            bnl[n] = *(bf16x8*)(Bls + (wc * 64 + n * 16 + fr) * 32 + fq * 8);
        #pragma unroll
        for (int m = 0; m < 4; ++m)
            #pragma unroll
            for (int n = 0; n < 4; ++n)
                acc[m][n] = __builtin_amdgcn_mfma_f32_16x16x32_bf16(amh[m], bnl[n], acc[m][n], 0, 0, 0);

        bf16x8 aml[4];
        #pragma unroll
        for (int m = 0; m < 4; ++m)
            aml[m] = *(bf16x8*)(Al + (wr * 64 + m * 16 + fr) * 32 + fq * 8);
        #pragma unroll
        for (int m = 0; m < 4; ++m)
            #pragma unroll
            for (int n = 0; n < 4; ++n)
                acc[m][n] = __builtin_amdgcn_mfma_f32_16x16x32_bf16(aml[m], bnh[n], acc[m][n], 0, 0, 0);
    }

    // ---- epilogue: C/D layout col=lane&15, row=(lane>>4)*4+reg
    if (nt < 8) {
        // write Vt[h=nt][b][d][j] directly; b constant per block
        const int b_ = (mt * 128) >> 9;
        const int jb0 = (mt & 3) * 128;
        unsigned short* vtw = Vt + (size_t)(nt * 16 + b_) * 128 * 512;
        #pragma unroll
        for (int m = 0; m < 4; ++m) {
            const int jb = jb0 + wr * 64 + m * 16 + fq * 4;
            float mk[4];
            #pragma unroll
            for (int r = 0; r < 4; ++r)
                mk[r] = nm[m0 + wr * 64 + m * 16 + fq * 4 + r];
            #pragma unroll
            for (int n = 0; n < 4; ++n) {
                const int d = wc * 64 + n * 16 + fr;
                u16x4 pk;
                #pragma unroll
                for (int r = 0; r < 4; ++r) pk[r] = f2bf(acc[m][n][r] * mk[r]);
                *(u16x4*)(vtw + (size_t)d * 512 + jb) = pk;
            }
        }
    } else {
        #pragma unroll
        for (int m = 0; m < 4; ++m) {
            #pragma unroll
            for (int r = 0; r < 4; ++r) {
                const int R = m0 + wr * 64 + m * 16 + fq * 4 + r;
                #pragma unroll
                for (int n = 0; n < 4; ++n) {
                    const int c = wc * 64 + n * 16 + fr;
                    if (c < 48) LR[(size_t)c * 8192 + R] = acc[m][n][r];
                }
            }
        }
    }
}

// ---------------------------------------------------------------------------
// Kernel 3b: adj int32 -> byte array adjB  [unchanged]
// ---------------------------------------------------------------------------
__global__ __launch_bounds__(256) void adjb_kernel(const int* __restrict__ adj,
                                                   unsigned char* __restrict__ adjB) {
    const int idx = blockIdx.x * 256 + threadIdx.x;
    const int4* s = (const int4*)(adj + (size_t)idx * 16);
    int4 v0 = s[0], v1 = s[1], v2 = s[2], v3 = s[3];
    union { unsigned char c[16]; int4 v; } o;
    o.c[0] = (unsigned char)v0.x; o.c[1] = (unsigned char)v0.y;
    o.c[2] = (unsigned char)v0.z; o.c[3] = (unsigned char)v0.w;
    o.c[4] = (unsigned char)v1.x; o.c[5] = (unsigned char)v1.y;
    o.c[6] = (unsigned char)v1.z; o.c[7] = (unsigned char)v1.w;
    o.c[8] = (unsigned char)v2.x; o.c[9] = (unsigned char)v2.y;
    o.c[10] = (unsigned char)v2.z; o.c[11] = (unsigned char)v2.w;
    o.c[12] = (unsigned char)v3.x; o.c[13] = (unsigned char)v3.y;
    o.c[14] = (unsigned char)v3.z; o.c[15] = (unsigned char)v3.w;
    *(int4*)(adjB + (size_t)idx * 16) = o.v;
}

// ---------------------------------------------------------------------------
// Kernel 4: fused attn  [unchanged — verified in round 10's 165us total]
// ---------------------------------------------------------------------------
__global__ __launch_bounds__(256, 4) void attn_kernel(const unsigned short* __restrict__ Vt,
                                                      const float* __restrict__ LR,
                                                      const unsigned char* __restrict__ adjB,
                                                      float* __restrict__ out) {
    __shared__ __align__(16) unsigned short Vb[2][16 * 512];
    __shared__ __align__(16) float rt[3 * 512];

    const int bid = blockIdx.x;
    const int itg = bid >> 7, hb = bid & 127, h = hb >> 4, b = hb & 15;
    const int tid = threadIdx.x, w = tid >> 6, lane = tid & 63;
    const int fr = lane & 15, fq = lane >> 4;
    const int i0 = (itg * 4 + w) * 16;
    const int fq8 = fq * 8;

    for (int idx = tid; idx < 1536; idx += 256) {
        int t = idx >> 9, j = idx & 511;
        rt[idx] = LR[(size_t)(24 + t * 8 + h) * 8192 + b * 512 + j];
    }
    const float lf0 = LR[(size_t)(h) * 8192 + b * 512 + i0 + fr];
    const float lf1 = LR[(size_t)(8 + h) * 8192 + b * 512 + i0 + fr];
    const float lf2 = LR[(size_t)(16 + h) * 8192 + b * 512 + i0 + fr];
    const unsigned char* arow = adjB + (size_t)(b * 512 + i0 + fr) * 512;
    const unsigned short* vt = Vt + (size_t)(h * 16 + b) * 128 * 512;

#define STAGE_V(bufp, os_) do {                                                   \
        _Pragma("unroll")                                                          \
        for (int q_ = 0; q_ < 4; ++q_) {                                           \
            const int nh_ = q_ * 4 + w;                                            \
            const unsigned short* src_ = vt + (size_t)((nh_ >> 1) * 16 + fr) * 512 \
                                          + (os_) * 64 + (nh_ & 1) * 32 + fq8;     \
            unsigned short* dst_ = (bufp) + nh_ * 512;                             \
            __builtin_amdgcn_global_load_lds(                                      \
                (const __attribute__((address_space(1))) void*)src_,               \
                (__attribute__((address_space(3))) void*)dst_, 16, 0, 0);          \
        }                                                                          \
    } while (0)

    STAGE_V(&Vb[0][0], 0);
    uint2 aA = *(const uint2*)(arow + fq8);
    uint2 aB = *(const uint2*)(arow + fq8 + 32);

    f32x4 acc[8];
    #pragma unroll
    for (int n = 0; n < 8; ++n) acc[n] = (f32x4){0.f, 0.f, 0.f, 0.f};
    float rsum = 0.f;

    __syncthreads();

    #pragma unroll 1
    for (int os = 0; os < 8; ++os) {
        unsigned short* vb = &Vb[os & 1][0];
        if (os < 7) STAGE_V(&Vb[(os & 1) ^ 1][0], os + 1);

        const int jA = os * 64 + fq8;
        const int jB = jA + 32;

        u16x8 vhA, vlA, vhB, vlB;
        {
            float4 r0a = *(const float4*)(rt + jA), r0b = *(const float4*)(rt + jA + 4);
            float4 r1a = *(const float4*)(rt + 512 + jA), r1b = *(const float4*)(rt + 512 + jA + 4);
            float4 r2a = *(const float4*)(rt + 1024 + jA), r2b = *(const float4*)(rt + 1024 + jA + 4);
            float e0[8] = {r0a.x, r0a.y, r0a.z, r0a.w, r0b.x, r0b.y, r0b.z, r0b.w};
            float e1[8] = {r1a.x, r1a.y, r1a.z, r1a.w, r1b.x, r1b.y, r1b.z, r1b.w};
            float e2[8] = {r2a.x, r2a.y, r2a.z, r2a.w, r2b.x, r2b.y, r2b.z, r2b.w};
            #pragma unroll
            for (int q = 0; q < 8; ++q) {
                unsigned av = ((q < 4 ? aA.x : aA.y) >> (8 * (q & 3))) & 255u;
                float sb = (av == 1u) ? (lf0 + e0[q])
                         : (av == 2u) ? (lf1 + e1[q]) : (lf2 + e2[q]);
                float sv = fmaxf(sb, 0.f) + 0.2f * fminf(sb, 0.f);
                float p = (av != 0u) ? __expf(sv) : 0.f;
                rsum += p;
                unsigned short hi = f2bf(p);
                vhA[q] = hi;
                vlA[q] = f2bf(p - b2f(hi));
            }
        }
        {
            float4 r0a = *(const float4*)(rt + jB), r0b = *(const float4*)(rt + jB + 4);
            float4 r1a = *(const float4*)(rt + 512 + jB), r1b = *(const float4*)(rt + 512 + jB + 4);
            float4 r2a = *(const float4*)(rt + 1024 + jB), r2b = *(const float4*)(rt + 1024 + jB + 4);
            float e0[8] = {r0a.x, r0a.y, r0a.z, r0a.w, r0b.x, r0b.y, r0b.z, r0b.w};
            float e1[8] = {r1a.x, r1a.y, r1a.z, r1a.w, r1b.x, r1b.y, r1b.z, r1b.w};
            float e2[8] = {r2a.x, r2a.y, r2a.z, r2a.w, r2b.x, r2b.y, r2b.z, r2b.w};
            #pragma unroll
            for (int q = 0; q < 8; ++q) {
                unsigned av = ((q < 4 ? aB.x : aB.y) >> (8 * (q & 3))) & 255u;
                float sb = (av == 1u) ? (lf0 + e0[q])
                         : (av == 2u) ? (lf1 + e1[q]) : (lf2 + e2[q]);
                float sv = fmaxf(sb, 0.f) + 0.2f * fminf(sb, 0.f);
                float p = (av != 0u) ? __expf(sv) : 0.f;
                rsum += p;
                unsigned short hi = f2bf(p);
                vhB[q] = hi;
                vlB[q] = f2bf(p - b2f(hi));
            }
        }
        if (os < 7) {
            aA = *(const uint2*)(arow + (os + 1) * 64 + fq8);
            aB = *(const uint2*)(arow + (os + 1) * 64 + fq8 + 32);
        }

        bf16x8 ahA = *(bf16x8*)&vhA, alA = *(bf16x8*)&vlA;
        bf16x8 ahB = *(bf16x8*)&vhB, alB = *(bf16x8*)&vlB;

        #pragma unroll
        for (int n = 0; n < 8; ++n) {
            bf16x8 vA = *(bf16x8*)(vb + (n * 2 + 0) * 512 + lane * 8);
            bf16x8 vB = *(bf16x8*)(vb + (n * 2 + 1) * 512 + lane * 8);
            acc[n] = __builtin_amdgcn_mfma_f32_16x16x32_bf16(ahA, vA, acc[n], 0, 0, 0);
            acc[n] = __builtin_amdgcn_mfma_f32_16x16x32_bf16(alA, vA, acc[n], 0, 0, 0);
            acc[n] = __builtin_amdgcn_mfma_f32_16x16x32_bf16(ahB, vB, acc[n], 0, 0, 0);
            acc[n] = __builtin_amdgcn_mfma_f32_16x16x32_bf16(alB, vB, acc[n], 0, 0, 0);
        }
        __syncthreads();
    }
#undef STAGE_V

    rsum += __shfl_xor(rsum, 16);
    rsum += __shfl_xor(rsum, 32);

    #pragma unroll
    for (int rr = 0; rr < 4; ++rr) {
        const int row = fq * 4 + rr;
        const float inv = 1.0f / __shfl(rsum, row);
        #pragma unroll
        for (int n = 0; n < 8; ++n) {
            out[(size_t)(b * 512 + i0 + row) * 1024 + h * 128 + n * 16 + fr] =
                fmaxf(acc[n][rr] * inv, 0.f);
        }
    }
}

// ---------------------------------------------------------------------------
extern "C" void kernel_launch(void* const* d_in, const int* in_sizes, int n_in,
                              void* d_out, int out_size, void* d_ws, size_t ws_size,
                              hipStream_t stream) {
    const float* x   = (const float*)d_in[0];
    const int*   adj = (const int*)d_in[1];
    const float* nm  = (const float*)d_in[2];
    const float* W   = (const float*)d_in[3];
    const float* a1  = (const float*)d_in[4];
    const float* a2  = (const float*)d_in[5];
    float* out = (float*)d_out;
    char* wsb = (char*)d_ws;

    unsigned short* Bh   = (unsigned short*)(wsb);
    unsigned short* Bl   = (unsigned short*)(wsb + 2359296);
    float*          LR   = (float*)(wsb + 21495808);
    unsigned short* Vt   = (unsigned short*)(wsb + 23068672);
    unsigned char*  adjB = (unsigned char*)(wsb + 39845888);

    hipLaunchKernelGGL(adjb_kernel, dim3(1024), dim3(256), 0, stream, adj, adjB);
    hipLaunchKernelGGL(pack_tr, dim3(128), dim3(256), 0, stream, W, Bh, Bl);
    hipLaunchKernelGGL(pack_wa, dim3(384), dim3(256), 0, stream, W, a1, a2, Bh, Bl);
    hipLaunchKernelGGL(pack_zero, dim3(80), dim3(256), 0, stream, Bh, Bl);
    hipLaunchKernelGGL(mgemm, dim3(576), dim3(256), 0, stream, x, Bh, Bl, nm, Vt, LR);
    hipLaunchKernelGGL(attn_kernel, dim3(1024), dim3(256), 0, stream, Vt, LR, adjB, out);
}